// Round 4
// baseline (204.600 us; speedup 1.0000x reference)
//
#include <hip/hip_runtime.h>

// Problem constants (match reference)
constexpr int T     = 4;
constexpr int NROWS = 1000000;
constexpr int B     = 16384;
constexpr int TOTAL = 16384 * 50; // 819200 lookups per table
constexpr int CHUNK = 4;          // lookups per thread

// Native clang vector types — required by __builtin_nontemporal_load
typedef float fv4 __attribute__((ext_vector_type(4)));
typedef int   iv4 __attribute__((ext_vector_type(4)));

// Kernel 1: p[t*NROWS + r] = dot(table[t][r], W), fully streaming (nt),
// plus fused out[:] = bias init (out must be bias-initialized before pool's atomics).
__global__ __launch_bounds__(256)
void row_dot_init_kernel(const fv4* __restrict__ tables,
                         const float* __restrict__ Wp,
                         const float* __restrict__ bias,
                         float* __restrict__ p,
                         float* __restrict__ out) {
    const float wx = Wp[0], wy = Wp[1], wz = Wp[2], ww = Wp[3];
    int i = blockIdx.x * blockDim.x + threadIdx.x;
    if (i < T * NROWS) {
        const fv4 r = __builtin_nontemporal_load(&tables[i]);
        float v = r.x * wx + r.y * wy + r.z * wz + r.w * ww;
        __builtin_nontemporal_store(v, &p[i]);
    }
    if (i < T * B) out[i] = bias[0];
}

// Kernel 2: gather 4B precomputed dots, run-length accumulate over sorted
// segment ids, flush via atomicAdd on segment change.
// XCD-pinning: table t is processed only by blocks with blockIdx%8 in
// {2t, 2t+1}, so each XCD's 4 MiB L2 holds exactly one table's 4 MB p slice.
__global__ __launch_bounds__(256)
void pool_p_kernel(const float* __restrict__ p,        // [T*NROWS]
                   const int*   __restrict__ indices,  // [T*TOTAL]
                   const int*   __restrict__ segids,   // [T*TOTAL] sorted per table
                   float*       __restrict__ out)      // [T*B]
{
    // 3200 blocks total; 800 blocks per table, each covering 256*4 = 1024 lookups.
    const int xcd    = blockIdx.x & 7;        // empirical XCD id (perf heuristic only)
    const int t      = xcd >> 1;              // table -> XCD pair {2t, 2t+1}
    const int within = (blockIdx.x >> 3) * 2 + (xcd & 1);  // [0, 800)

    const int local = within * (256 * CHUNK) + threadIdx.x * CHUNK;

    const iv4* idx4 = (const iv4*)(indices + t * TOTAL + local); // 16B aligned
    const iv4* seg4 = (const iv4*)(segids  + t * TOTAL + local);
    const float* pt  = p + t * NROWS;
    float* outt      = out + t * B;

    // Non-temporal: streaming index data must not evict the L2-resident p.
    const iv4 ia = __builtin_nontemporal_load(idx4);
    const iv4 sa = __builtin_nontemporal_load(seg4);

    const int ix[4] = {ia.x, ia.y, ia.z, ia.w};
    const int ss[4] = {sa.x, sa.y, sa.z, sa.w};

    // Issue all 4 independent gathers before the serial scan
    float v[4];
    #pragma unroll
    for (int j = 0; j < 4; ++j) v[j] = pt[ix[j]];

    float acc = 0.0f;
    int   cur = ss[0];
    #pragma unroll
    for (int j = 0; j < 4; ++j) {
        if (ss[j] != cur) {
            atomicAdd(&outt[cur], acc);
            acc = 0.0f;
            cur = ss[j];
        }
        acc += v[j];
    }
    atomicAdd(&outt[cur], acc);
}

extern "C" void kernel_launch(void* const* d_in, const int* in_sizes, int n_in,
                              void* d_out, int out_size, void* d_ws, size_t ws_size,
                              hipStream_t stream) {
    const fv4*   tables  = (const fv4*)d_in[0];      // [T, N, 4] f32
    const float* W       = (const float*)d_in[1];    // [1, 4]   f32
    const float* bias    = (const float*)d_in[2];    // [1]      f32
    const int*   indices = (const int*)d_in[3];      // [T, TOTAL]
    const int*   segids  = (const int*)d_in[4];      // [T, TOTAL]
    float*       out     = (float*)d_out;            // [T*B] f32

    float* p = (float*)d_ws;                         // 16 MB scratch

    {
        int n = T * NROWS;                           // 4,000,000 (covers T*B too)
        row_dot_init_kernel<<<(n + 255) / 256, 256, 0, stream>>>(tables, W, bias, p, out);
    }
    {
        // 800 blocks/table * 4 tables; blockIdx%8 encodes the XCD pair.
        pool_p_kernel<<<3200, 256, 0, stream>>>(p, indices, segids, out);
    }
}

// Round 5
// 150.657 us; speedup vs baseline: 1.3581x; 1.3581x over previous
//
#include <hip/hip_runtime.h>

// Problem constants (match reference)
constexpr int T     = 4;
constexpr int NROWS = 1000000;
constexpr int B     = 16384;
constexpr int TOTAL = 16384 * 50; // 819200 lookups per table

// Native clang vector type — required by __builtin_nontemporal_load
typedef float fv4 __attribute__((ext_vector_type(4)));

// ws layout: p[T*NROWS] floats (16 MB), then offsets[T*(B+1)] ints (256 KB)

// Producer: p[t*NROWS + r] = dot(table[t][r], W)   (streaming, nt)
//           offsets[t][b]  = first local i with segids[t][i] >= b
// Fused so one launch covers both (4M threads >= 3.28M positions).
__global__ __launch_bounds__(256)
void produce_kernel(const fv4*  __restrict__ tables,
                    const float* __restrict__ Wp,
                    const int*  __restrict__ segids,
                    float* __restrict__ p,
                    int*   __restrict__ offsets) {
    const int i = blockIdx.x * blockDim.x + threadIdx.x;

    if (i < T * NROWS) {
        const float wx = Wp[0], wy = Wp[1], wz = Wp[2], ww = Wp[3];
        const fv4 r = __builtin_nontemporal_load(&tables[i]);
        float v = r.x * wx + r.y * wy + r.z * wz + r.w * ww;
        __builtin_nontemporal_store(v, &p[i]);
    }

    if (i < T * TOTAL) {
        const int t     = i / TOTAL;
        const int local = i - t * TOTAL;
        const int seg   = __builtin_nontemporal_load(&segids[i]);
        const int prev  = (local == 0) ? -1 : __builtin_nontemporal_load(&segids[i - 1]);
        int* offs = offsets + t * (B + 1);
        for (int b = prev + 1; b <= seg; ++b) offs[b] = local;   // boundary (+ gap fill)
        if (local == TOTAL - 1) {
            for (int b = seg + 1; b <= B; ++b) offs[b] = TOTAL;  // trailing empties + sentinel
        }
    }
}

// Pool: 4 lanes per bag, no atomics. XCD-pinned: table t -> XCD pair {2t,2t+1}
// so each XCD's 4 MiB L2 holds exactly its table's 4 MB p slice.
__global__ __launch_bounds__(256)
void pool_kernel(const float* __restrict__ p,        // [T*NROWS]
                 const int*   __restrict__ indices,  // [T*TOTAL]
                 const int*   __restrict__ offsets,  // [T*(B+1)]
                 const float* __restrict__ bias,
                 float*       __restrict__ out)      // [T*B]
{
    // 1024 blocks: 256 per table, each block covers 64 bags (4 lanes/bag).
    const int xcd    = blockIdx.x & 7;
    const int t      = xcd >> 1;
    const int within = (blockIdx.x >> 3) * 2 + (xcd & 1);   // [0, 256)

    const int lane4 = threadIdx.x & 3;
    const int bag   = within * 64 + (threadIdx.x >> 2);

    const int* offs = offsets + t * (B + 1);
    const int start = offs[bag];
    const int end   = offs[bag + 1];

    const int*   idx = indices + t * TOTAL;
    const float* pt  = p + t * NROWS;

    float acc = 0.0f;
    #pragma unroll 4
    for (int i = start + lane4; i < end; i += 4) {
        acc += pt[__builtin_nontemporal_load(&idx[i])];
    }

    acc += __shfl_xor(acc, 1);
    acc += __shfl_xor(acc, 2);

    if (lane4 == 0) out[t * B + bag] = acc + bias[0];
}

extern "C" void kernel_launch(void* const* d_in, const int* in_sizes, int n_in,
                              void* d_out, int out_size, void* d_ws, size_t ws_size,
                              hipStream_t stream) {
    const fv4*   tables  = (const fv4*)d_in[0];      // [T, N, 4] f32
    const float* W       = (const float*)d_in[1];    // [1, 4]   f32
    const float* bias    = (const float*)d_in[2];    // [1]      f32
    const int*   indices = (const int*)d_in[3];      // [T, TOTAL]
    const int*   segids  = (const int*)d_in[4];      // [T, TOTAL] sorted per table
    float*       out     = (float*)d_out;            // [T*B] f32

    float* p       = (float*)d_ws;                   // 16 MB
    int*   offsets = (int*)((char*)d_ws + (size_t)T * NROWS * sizeof(float)); // 256 KB

    {
        int n = T * NROWS;                           // 4,000,000 (covers T*TOTAL too)
        produce_kernel<<<(n + 255) / 256, 256, 0, stream>>>(tables, W, segids, p, offsets);
    }
    {
        // 4 lanes/bag * 16384 bags * 4 tables = 262,144 threads = 1024 blocks
        pool_kernel<<<1024, 256, 0, stream>>>(p, indices, offsets, bias, out);
    }
}

// Round 6
// 134.758 us; speedup vs baseline: 1.5183x; 1.1180x over previous
//
#include <hip/hip_runtime.h>

// Problem constants (match reference)
constexpr int T     = 4;
constexpr int NROWS = 1000000;
constexpr int B     = 16384;
constexpr int TOTAL = 16384 * 50; // 819200 lookups per table

// Native clang vector type — required by __builtin_nontemporal_load
typedef float fv4 __attribute__((ext_vector_type(4)));

// ws layout: p[T*NROWS] floats (16 MB)

// Producer: p[t*NROWS + r] = dot(table[t][r], W), pure stream.
// Fused out[:] = bias init (pool's atomics accumulate on top of bias).
__global__ __launch_bounds__(256)
void produce_kernel(const fv4*   __restrict__ tables,
                    const float* __restrict__ Wp,
                    const float* __restrict__ bias,
                    float* __restrict__ p,
                    float* __restrict__ out) {
    const int i = blockIdx.x * 256 + threadIdx.x;
    if (i < T * NROWS) {
        const float wx = Wp[0], wy = Wp[1], wz = Wp[2], ww = Wp[3];
        const fv4 r = tables[i];               // likely L3-resident from d_in restore
        p[i] = r.x * wx + r.y * wy + r.z * wz + r.w * ww;  // normal store: stay cached
    }
    if (i < T * B) out[i] = bias[0];
}

// Pool: one lookup per thread, no loops. Wave-level segmented inclusive scan
// over sorted segment ids (conditional Hillis-Steele — valid because equal
// segs are contiguous); only the last lane of each run flushes via atomicAdd.
// ~102k atomics over 65k addresses => ~2 per address, no serialization.
// XCD-pinned: table t -> XCD pair {2t,2t+1} so each XCD's 4 MiB L2 holds
// exactly its table's 4 MB p slice; idx/seg loads are non-temporal so the
// 26 MB stream doesn't evict p.
__global__ __launch_bounds__(256)
void pool_kernel(const float* __restrict__ p,        // [T*NROWS]
                 const int*   __restrict__ indices,  // [T*TOTAL]
                 const int*   __restrict__ segids,   // [T*TOTAL] sorted per table
                 float*       __restrict__ out)      // [T*B], pre-set to bias
{
    // 12800 blocks: 3200 per table (256 lookups each). blockIdx%8 ~ XCD id.
    const int xcd    = blockIdx.x & 7;
    const int t      = xcd >> 1;
    const int within = (blockIdx.x >> 3) * 2 + (xcd & 1);   // [0, 3200)
    const int local  = within * 256 + threadIdx.x;
    const int g      = t * TOTAL + local;

    const int lane = threadIdx.x & 63;

    const int seg = __builtin_nontemporal_load(&segids[g]);
    const int idx = __builtin_nontemporal_load(&indices[g]);
    float v = p[t * NROWS + idx];

    // Segmented inclusive scan across the 64-lane wave.
    #pragma unroll
    for (int d = 1; d < 64; d <<= 1) {
        const float ov = __shfl_up(v, d, 64);
        const int   os = __shfl_up(seg, d, 64);
        if (lane >= d && os == seg) v += ov;
    }

    // Last lane of each same-seg run in this wave flushes the run sum.
    const int nseg = __shfl_down(seg, 1, 64);
    if (lane == 63 || nseg != seg) {
        atomicAdd(&out[t * B + seg], v);
    }
}

extern "C" void kernel_launch(void* const* d_in, const int* in_sizes, int n_in,
                              void* d_out, int out_size, void* d_ws, size_t ws_size,
                              hipStream_t stream) {
    const fv4*   tables  = (const fv4*)d_in[0];      // [T, N, 4] f32
    const float* W       = (const float*)d_in[1];    // [1, 4]   f32
    const float* bias    = (const float*)d_in[2];    // [1]      f32
    const int*   indices = (const int*)d_in[3];      // [T, TOTAL]
    const int*   segids  = (const int*)d_in[4];      // [T, TOTAL] sorted per table
    float*       out     = (float*)d_out;            // [T*B] f32

    float* p = (float*)d_ws;                         // 16 MB scratch

    {
        int n = T * NROWS;                           // 4,000,000 (covers T*B init too)
        produce_kernel<<<(n + 255) / 256, 256, 0, stream>>>(tables, W, bias, p, out);
    }
    {
        // T*TOTAL = 3,276,800 threads = 12,800 blocks (multiple of 8 for pinning)
        pool_kernel<<<12800, 256, 0, stream>>>(p, indices, segids, out);
    }
}